// Round 1
// baseline (778.709 us; speedup 1.0000x reference)
//
#include <hip/hip_runtime.h>
#include <math.h>

#define BB 8
#define CIN 64
#define COUT 64
#define HH 128
#define WW 128
#define HW (HH*WW)
#define K2 9
#define EPSV 1e-5f

// ---------------- Kernel: transpose w_dcn (o,c,k) -> wt (k,c,o) ----------------
__global__ void transpose_w(const float* __restrict__ w_dcn, float* __restrict__ wt) {
    int i = blockIdx.x * 256 + threadIdx.x;   // i = k*4096 + c*64 + o
    if (i < 36864) {
        int k = i >> 12;
        int c = (i >> 6) & 63;
        int o = i & 63;
        wt[i] = w_dcn[(o * 64 + c) * 9 + k];
    }
}

// ---------------- Kernel: offset + mask conv (27 output channels) ----------------
// outputs: dy[b][k][h][w], dx[b][k][h][w], mask[b][k][h][w]
__global__ __launch_bounds__(256) void conv_offmask(
    const float* __restrict__ x,
    const float* __restrict__ w_off, const float* __restrict__ b_off,
    const float* __restrict__ w_mask, const float* __restrict__ b_mask,
    float* __restrict__ dyp, float* __restrict__ dxp, float* __restrict__ mkp)
{
    // LDS weights: swt[(cin*9+kk)*28 + oc], oc 0..17 = w_off, 18..26 = w_mask
    __shared__ float swt[576 * 28];
    for (int i = threadIdx.x; i < 10368; i += 256) {  // w_off: oc*576 + r
        int oc = i / 576, r = i % 576;
        swt[r * 28 + oc] = w_off[i];
    }
    for (int i = threadIdx.x; i < 5184; i += 256) {   // w_mask
        int oc = i / 576, r = i % 576;
        swt[r * 28 + 18 + oc] = w_mask[i];
    }
    __syncthreads();

    int p = blockIdx.x * 256 + threadIdx.x;           // pixel id over B*H*W
    int b = p / HW;
    int rem = p % HW;
    int h = rem / WW;
    int w = rem % WW;

    float acc[27];
#pragma unroll
    for (int oc = 0; oc < 27; ++oc) acc[oc] = 0.f;

    const float* xb = x + b * CIN * HW;
    for (int cin = 0; cin < CIN; ++cin) {
        const float* xp = xb + cin * HW;
#pragma unroll
        for (int ky = 0; ky < 3; ++ky) {
            int yy = h + ky - 1;
            bool vy = (yy >= 0) && (yy < HH);
#pragma unroll
            for (int kx = 0; kx < 3; ++kx) {
                int xx = w + kx - 1;
                float xv = (vy && xx >= 0 && xx < WW) ? xp[yy * WW + xx] : 0.f;
                const float* wsl = &swt[(cin * 9 + ky * 3 + kx) * 28];
#pragma unroll
                for (int oc = 0; oc < 27; ++oc) acc[oc] += xv * wsl[oc];
            }
        }
    }

#pragma unroll
    for (int k = 0; k < K2; ++k) {
        float dv = acc[2 * k]     + b_off[2 * k];
        float dx = acc[2 * k + 1] + b_off[2 * k + 1];
        float mv = acc[18 + k]    + b_mask[k];
        mv = 1.f / (1.f + expf(-mv));
        int oidx = (b * K2 + k) * HW + rem;
        dyp[oidx] = dv;
        dxp[oidx] = dx;
        mkp[oidx] = mv;
    }
}

// ---------------- Kernel: deformable sampling + 64x(64*9) conv ----------------
__global__ __launch_bounds__(256) void dcn_main(
    const float* __restrict__ x, const float* __restrict__ wt,
    const float* __restrict__ dyp, const float* __restrict__ dxp,
    const float* __restrict__ mkp, const float* __restrict__ b_dcn,
    float* __restrict__ pre)
{
    __shared__ float sw[4096];   // wt slice [c][o] for current k
    int tid = threadIdx.x;
    int p = blockIdx.x * 256 + tid;
    int b = p / HW;
    int rem = p % HW;
    int h = rem / WW;
    int w = rem % WW;
    const float* xb = x + b * CIN * HW;

    float acc[COUT];
#pragma unroll
    for (int o = 0; o < COUT; ++o) acc[o] = 0.f;

    for (int k = 0; k < K2; ++k) {
        __syncthreads();
#pragma unroll
        for (int i = 0; i < 16; ++i) sw[tid + 256 * i] = wt[k * 4096 + tid + 256 * i];
        __syncthreads();

        int idx = (b * K2 + k) * HW + rem;
        float dyv = dyp[idx], dxv = dxp[idx], mv = mkp[idx];
        float py = (float)(h + (k / 3) - 1) + dyv;
        float px = (float)(w + (k % 3) - 1) + dxv;
        float y0f = floorf(py), x0f = floorf(px);
        float ly = py - y0f, lx = px - x0f;
        int y0 = (int)y0f, x0 = (int)x0f;
        int y1 = y0 + 1, x1 = x0 + 1;
        float fy0 = (y0 >= 0 && y0 < HH) ? 1.f : 0.f;
        float fy1 = (y1 >= 0 && y1 < HH) ? 1.f : 0.f;
        float fx0 = (x0 >= 0 && x0 < WW) ? 1.f : 0.f;
        float fx1 = (x1 >= 0 && x1 < WW) ? 1.f : 0.f;
        int yc0 = min(max(y0, 0), HH - 1), yc1 = min(max(y1, 0), HH - 1);
        int xc0 = min(max(x0, 0), WW - 1), xc1 = min(max(x1, 0), WW - 1);
        int o00 = yc0 * WW + xc0, o01 = yc0 * WW + xc1;
        int o10 = yc1 * WW + xc0, o11 = yc1 * WW + xc1;
        float w00 = (1.f - ly) * (1.f - lx) * mv * fy0 * fx0;
        float w01 = (1.f - ly) * lx * mv * fy0 * fx1;
        float w10 = ly * (1.f - lx) * mv * fy1 * fx0;
        float w11 = ly * lx * mv * fy1 * fx1;

#pragma unroll 2
        for (int c = 0; c < CIN; ++c) {
            const float* xc = xb + c * HW;
            float val = xc[o00] * w00 + xc[o01] * w01 + xc[o10] * w10 + xc[o11] * w11;
            const float* swc = &sw[c * 64];
#pragma unroll
            for (int o = 0; o < COUT; ++o) acc[o] += val * swc[o];
        }
    }

    int obase = b * COUT * HW + rem;
#pragma unroll
    for (int o = 0; o < COUT; ++o) pre[obase + o * HW] = acc[o] + b_dcn[o];
}

// ---------------- Kernel: BN statistics ----------------
__global__ __launch_bounds__(256) void bn_stats(
    const float* __restrict__ pre, float* __restrict__ sums, float* __restrict__ sums2)
{
    int c = blockIdx.x & 63;
    int q = blockIdx.x >> 6;   // quarter 0..3
    float s = 0.f, s2 = 0.f;
    for (int b = 0; b < BB; ++b) {
        const float* p = pre + (b * COUT + c) * HW + q * 4096;
        for (int i = threadIdx.x; i < 4096; i += 256) {
            float v = p[i];
            s += v;
            s2 += v * v;
        }
    }
#pragma unroll
    for (int off = 32; off > 0; off >>= 1) {
        s  += __shfl_down(s, off);
        s2 += __shfl_down(s2, off);
    }
    __shared__ float ls[8];
    int wid = threadIdx.x >> 6, lane = threadIdx.x & 63;
    if (lane == 0) { ls[wid] = s; ls[wid + 4] = s2; }
    __syncthreads();
    if (threadIdx.x == 0) {
        atomicAdd(&sums[c],  ls[0] + ls[1] + ls[2] + ls[3]);
        atomicAdd(&sums2[c], ls[4] + ls[5] + ls[6] + ls[7]);
    }
}

// ---------------- Kernel: BN apply + Mish ----------------
__global__ __launch_bounds__(256) void bn_mish(
    const float* __restrict__ pre, const float* __restrict__ sums,
    const float* __restrict__ sums2, const float* __restrict__ gamma,
    const float* __restrict__ beta, float* __restrict__ out)
{
    int idx = blockIdx.x * 256 + threadIdx.x;
    int c = (idx >> 14) & 63;
    const float invN = 1.f / (float)(BB * HW);
    float mean = sums[c] * invN;
    float var = sums2[c] * invN - mean * mean;
    float v = (pre[idx] - mean) * rsqrtf(var + EPSV);
    v = v * gamma[c] + beta[c];
    float sp = fmaxf(v, 0.f) + log1pf(expf(-fabsf(v)));
    out[idx] = v * tanhf(sp);
}

extern "C" void kernel_launch(void* const* d_in, const int* in_sizes, int n_in,
                              void* d_out, int out_size, void* d_ws, size_t ws_size,
                              hipStream_t stream) {
    const float* x      = (const float*)d_in[0];
    const float* w_off  = (const float*)d_in[1];
    const float* b_off  = (const float*)d_in[2];
    const float* w_mask = (const float*)d_in[3];
    const float* b_mask = (const float*)d_in[4];
    const float* w_dcn  = (const float*)d_in[5];
    const float* b_dcn  = (const float*)d_in[6];
    const float* gamma  = (const float*)d_in[7];
    const float* beta   = (const float*)d_in[8];
    float* out = (float*)d_out;

    float* ws   = (float*)d_ws;
    float* wt   = ws;                       // 36864
    float* dyp  = wt + 36864;               // 1179648
    float* dxp  = dyp + 1179648;            // 1179648
    float* mkp  = dxp + 1179648;            // 1179648
    float* prep = mkp + 1179648;            // 8388608
    float* sums = prep + 8388608;           // 64
    float* sums2 = sums + 64;               // 64

    hipMemsetAsync(sums, 0, 2 * 64 * sizeof(float), stream);

    transpose_w<<<144, 256, 0, stream>>>(w_dcn, wt);
    conv_offmask<<<512, 256, 0, stream>>>(x, w_off, b_off, w_mask, b_mask, dyp, dxp, mkp);
    dcn_main<<<512, 256, 0, stream>>>(x, wt, dyp, dxp, mkp, b_dcn, prep);
    bn_stats<<<256, 256, 0, stream>>>(prep, sums, sums2);
    bn_mish<<<32768, 256, 0, stream>>>(prep, sums, sums2, gamma, beta, out);
}

// Round 2
// 299.580 us; speedup vs baseline: 2.5993x; 2.5993x over previous
//
#include <hip/hip_runtime.h>
#include <math.h>

#define BB 8
#define CIN 64
#define COUT 64
#define HH 128
#define WW 128
#define HW (HH*WW)
#define EPSV 1e-5f

typedef __attribute__((ext_vector_type(8))) short bf16x8;
typedef __attribute__((ext_vector_type(4))) float f32x4;

__device__ __forceinline__ short f2bf(float f) {
    unsigned u = __builtin_bit_cast(unsigned, f);
    unsigned r = (u + 0x7fffu + ((u >> 16) & 1u)) >> 16;
    return (short)r;
}

// ---- pack w_dcn (o,c,k) -> B-fragment order: [(ks*4+nf)*64+lane]*8+e, t=ks*32+(lane>>4)*8+e, o=nf*16+(lane&15)
__global__ void pack_wdcn(const float* __restrict__ w_dcn, short* __restrict__ wtf) {
    int i = blockIdx.x * 256 + threadIdx.x;
    if (i >= 18 * 4 * 64 * 8) return;
    int e = i & 7, lane = (i >> 3) & 63, nf = (i >> 9) & 3, ks = i >> 11;
    int t = ks * 32 + ((lane >> 4) << 3) + e;
    int o = (nf << 4) + (lane & 15);
    int k = t >> 6, c = t & 63;
    wtf[i] = f2bf(w_dcn[(o * 64 + c) * 9 + k]);
}

// ---- pack w_off(18,c,k) + w_mask(9,c,k) -> [(ks*2+nf)*64+lane]*8+e, cols 27..31 zero
__global__ void pack_woff(const float* __restrict__ w_off, const float* __restrict__ w_mask,
                          short* __restrict__ wtf) {
    int i = blockIdx.x * 256 + threadIdx.x;
    if (i >= 18 * 2 * 64 * 8) return;
    int e = i & 7, lane = (i >> 3) & 63, nf = (i >> 9) & 1, ks = i >> 10;
    int t = ks * 32 + ((lane >> 4) << 3) + e;
    int oc = (nf << 4) + (lane & 15);
    int k = t >> 6, c = t & 63;
    float v = 0.f;
    if (oc < 18) v = w_off[(oc * 64 + c) * 9 + k];
    else if (oc < 27) v = w_mask[((oc - 18) * 64 + c) * 9 + k];
    wtf[i] = f2bf(v);
}

// ---- fused conv via MFMA. NF=2: offset/mask conv (writes dy/dx/mask).
//      NF=4, DEFORM: deformable sampling + main conv (writes pre).
template<int NF, bool DEFORM>
__global__ __launch_bounds__(256) void conv_mfma(
    const float* __restrict__ x, const short* __restrict__ wtf,
    float* __restrict__ dyp, float* __restrict__ dxp, float* __restrict__ mkp,
    const float* __restrict__ bias1, const float* __restrict__ bias2,
    float* __restrict__ pre)
{
    __shared__ __align__(16) short wlds[18 * NF * 64 * 8];
    __shared__ __align__(16) short alds[2][2048];

    const int tid = threadIdx.x;
    {   // preload weights to LDS (contiguous 16B chunks)
        const f32x4* src = (const f32x4*)wtf;
        f32x4* dst = (f32x4*)wlds;
        const int n16 = 18 * NF * 64;
        for (int i = tid; i < n16; i += 256) dst[i] = src[i];
    }

    // XCD-bijective swizzle: 2048 blocks % 8 == 0 -> one full image per XCD
    const int bid = blockIdx.x;
    const int tile = (bid & 7) * 256 + (bid >> 3);

    const int pbase = tile << 6;                 // 64 consecutive pixels (same b, same h)
    const int b = pbase / HW;
    const int rembase = pbase % HW;
    const int lanep = tid & 63;                  // pixel within tile (sampling role)
    const int c_off = tid >> 6;                  // c-octet (sampling role)
    const int rem = rembase + lanep;
    const int hh = rem >> 7;
    const int wwp = rem & 127;
    const float* xb = x + b * CIN * HW;

    // A-fragment LDS slot this thread fills: [wm=p>>4][lane=(p&15)|(c_off<<4)][e]
    short* adst = &alds[0][(((lanep >> 4) * 64) + ((lanep & 15) | (c_off << 4))) * 8];

    f32x4 acc[NF];
#pragma unroll
    for (int nf = 0; nf < NF; ++nf) acc[nf] = (f32x4){0.f, 0.f, 0.f, 0.f};

    auto stage = [&](int ks, int buf) {
        const int k = ks >> 1;
        const int cb = (ks & 1) << 5;
        bf16x8 vals;
        if constexpr (DEFORM) {
            int idx = (b * 9 + k) * HW + rem;
            float dyv = dyp[idx], dxv = dxp[idx], mv = mkp[idx];
            float py = (float)(hh + (k / 3) - 1) + dyv;
            float px = (float)(wwp + (k % 3) - 1) + dxv;
            float y0f = floorf(py), x0f = floorf(px);
            float ly = py - y0f, lx = px - x0f;
            int y0 = (int)y0f, x0 = (int)x0f;
            int y1 = y0 + 1, x1 = x0 + 1;
            float fy0 = (y0 >= 0 && y0 < HH) ? 1.f : 0.f;
            float fy1 = (y1 >= 0 && y1 < HH) ? 1.f : 0.f;
            float fx0 = (x0 >= 0 && x0 < WW) ? 1.f : 0.f;
            float fx1 = (x1 >= 0 && x1 < WW) ? 1.f : 0.f;
            int yc0 = min(max(y0, 0), HH - 1), yc1 = min(max(y1, 0), HH - 1);
            int xc0 = min(max(x0, 0), WW - 1), xc1 = min(max(x1, 0), WW - 1);
            int o00 = yc0 * WW + xc0, o01 = yc0 * WW + xc1;
            int o10 = yc1 * WW + xc0, o11 = yc1 * WW + xc1;
            float w00 = (1.f - ly) * (1.f - lx) * mv * fy0 * fx0;
            float w01 = (1.f - ly) * lx * mv * fy0 * fx1;
            float w10 = ly * (1.f - lx) * mv * fy1 * fx0;
            float w11 = ly * lx * mv * fy1 * fx1;
            const float* xc = xb + (cb + c_off * 8) * HW;
#pragma unroll
            for (int i = 0; i < 8; ++i) {
                float v = xc[o00] * w00 + xc[o01] * w01 + xc[o10] * w10 + xc[o11] * w11;
                vals[i] = f2bf(v);
                xc += HW;
            }
        } else {
            int yy = hh + (k / 3) - 1;
            int xx = wwp + (k % 3) - 1;
            bool ok = (yy >= 0) && (yy < HH) && (xx >= 0) && (xx < WW);
            const float* xc = xb + (cb + c_off * 8) * HW + yy * WW + xx;
#pragma unroll
            for (int i = 0; i < 8; ++i) {
                float v = ok ? xc[i * HW] : 0.f;
                vals[i] = f2bf(v);
            }
        }
        *(bf16x8*)(adst + buf * 2048) = vals;
    };

    stage(0, 0);
    int s = 0;
    const int lane = tid & 63, wm = tid >> 6;
#pragma unroll 1
    for (int ks = 0; ks < 18; ++ks) {
        __syncthreads();
        if (ks + 1 < 18) stage(ks + 1, s ^ 1);
        bf16x8 af = *(const bf16x8*)&alds[s][(wm * 64 + lane) * 8];
#pragma unroll
        for (int nf = 0; nf < NF; ++nf) {
            bf16x8 bfr = *(const bf16x8*)&wlds[((ks * NF + nf) * 64 + lane) * 8];
            acc[nf] = __builtin_amdgcn_mfma_f32_16x16x32_bf16(af, bfr, acc[nf], 0, 0, 0);
        }
        s ^= 1;
    }

    // epilogue: C/D map col=lane&15, row=(lane>>4)*4+j
    const int colb = lane & 15, rq = lane >> 4;
    const int prow = wm * 16 + rq * 4;
    if constexpr (DEFORM) {
#pragma unroll
        for (int nf = 0; nf < NF; ++nf) {
            int o = nf * 16 + colb;
            float bo = bias1[o];
            float* dst = pre + (b * COUT + o) * HW + rembase + prow;
#pragma unroll
            for (int j = 0; j < 4; ++j) dst[j] = acc[nf][j] + bo;
        }
    } else {
#pragma unroll
        for (int nf = 0; nf < NF; ++nf) {
            int oc = nf * 16 + colb;
            if (oc < 18) {
                int k = oc >> 1;
                float bo = bias1[oc];
                float* dst = ((oc & 1) ? dxp : dyp) + (b * 9 + k) * HW + rembase + prow;
#pragma unroll
                for (int j = 0; j < 4; ++j) dst[j] = acc[nf][j] + bo;
            } else if (oc < 27) {
                int k = oc - 18;
                float bo = bias2[k];
                float* dst = mkp + (b * 9 + k) * HW + rembase + prow;
#pragma unroll
                for (int j = 0; j < 4; ++j) dst[j] = 1.f / (1.f + expf(-(acc[nf][j] + bo)));
            }
        }
    }
}

// ---------------- BN statistics ----------------
__global__ __launch_bounds__(256) void bn_stats(
    const float* __restrict__ pre, float* __restrict__ sums, float* __restrict__ sums2)
{
    int c = blockIdx.x & 63;
    int q = blockIdx.x >> 6;
    float s = 0.f, s2 = 0.f;
    for (int b = 0; b < BB; ++b) {
        const f32x4* p = (const f32x4*)(pre + (b * COUT + c) * HW + q * 4096);
        for (int i = threadIdx.x; i < 1024; i += 256) {
            f32x4 v = p[i];
            s += v.x + v.y + v.z + v.w;
            s2 += v.x * v.x + v.y * v.y + v.z * v.z + v.w * v.w;
        }
    }
#pragma unroll
    for (int off = 32; off > 0; off >>= 1) {
        s  += __shfl_down(s, off);
        s2 += __shfl_down(s2, off);
    }
    __shared__ float ls[8];
    int wid = threadIdx.x >> 6, lanei = threadIdx.x & 63;
    if (lanei == 0) { ls[wid] = s; ls[wid + 4] = s2; }
    __syncthreads();
    if (threadIdx.x == 0) {
        atomicAdd(&sums[c],  ls[0] + ls[1] + ls[2] + ls[3]);
        atomicAdd(&sums2[c], ls[4] + ls[5] + ls[6] + ls[7]);
    }
}

// ---------------- BN apply + Mish (float4) ----------------
__global__ __launch_bounds__(256) void bn_mish(
    const float* __restrict__ pre, const float* __restrict__ sums,
    const float* __restrict__ sums2, const float* __restrict__ gamma,
    const float* __restrict__ beta, float* __restrict__ out)
{
    int vid = blockIdx.x * 256 + threadIdx.x;       // float4 index
    int c = (vid >> 12) & 63;                       // (vid*4 >> 14) & 63
    const float invN = 1.f / (float)(BB * HW);
    float mean = sums[c] * invN;
    float rstd = rsqrtf(sums2[c] * invN - mean * mean + EPSV);
    float g = gamma[c], be = beta[c];
    f32x4 v = ((const f32x4*)pre)[vid];
    f32x4 r;
#pragma unroll
    for (int j = 0; j < 4; ++j) {
        float t = (v[j] - mean) * rstd * g + be;
        float sp = fmaxf(t, 0.f) + log1pf(expf(-fabsf(t)));
        r[j] = t * tanhf(sp);
    }
    ((f32x4*)out)[vid] = r;
}

extern "C" void kernel_launch(void* const* d_in, const int* in_sizes, int n_in,
                              void* d_out, int out_size, void* d_ws, size_t ws_size,
                              hipStream_t stream) {
    const float* x      = (const float*)d_in[0];
    const float* w_off  = (const float*)d_in[1];
    const float* b_off  = (const float*)d_in[2];
    const float* w_mask = (const float*)d_in[3];
    const float* b_mask = (const float*)d_in[4];
    const float* w_dcn  = (const float*)d_in[5];
    const float* b_dcn  = (const float*)d_in[6];
    const float* gamma  = (const float*)d_in[7];
    const float* beta   = (const float*)d_in[8];
    float* out = (float*)d_out;

    short* wtf_off = (short*)d_ws;                    // 18432 shorts = 36864 B
    short* wtf_dcn = wtf_off + 18432;                 // 36864 shorts = 73728 B
    float* fws  = (float*)(wtf_dcn + 36864);          // 16B-aligned (110592 B offset)
    float* dyp  = fws;                                // 1179648
    float* dxp  = dyp + 1179648;
    float* mkp  = dxp + 1179648;
    float* prep = mkp + 1179648;                      // 8388608
    float* sums = prep + 8388608;
    float* sums2 = sums + 64;

    hipMemsetAsync(sums, 0, 2 * 64 * sizeof(float), stream);

    pack_woff<<<72, 256, 0, stream>>>(w_off, w_mask, wtf_off);
    pack_wdcn<<<144, 256, 0, stream>>>(w_dcn, wtf_dcn);
    conv_mfma<2, false><<<2048, 256, 0, stream>>>(x, wtf_off, dyp, dxp, mkp, b_off, b_mask, nullptr);
    conv_mfma<4, true ><<<2048, 256, 0, stream>>>(x, wtf_dcn, dyp, dxp, mkp, b_dcn, nullptr, prep);
    bn_stats<<<256, 256, 0, stream>>>(prep, sums, sums2);
    bn_mish<<<8192, 256, 0, stream>>>(prep, sums, sums2, gamma, beta, out);
}

// Round 3
// 258.723 us; speedup vs baseline: 3.0098x; 1.1579x over previous
//
#include <hip/hip_runtime.h>
#include <math.h>

#define BB 8
#define CIN 64
#define COUT 64
#define HH 128
#define WW 128
#define HW (HH*WW)
#define EPSV 1e-5f

typedef __attribute__((ext_vector_type(8))) short bf16x8;
typedef __attribute__((ext_vector_type(4))) float f32x4;

__device__ __forceinline__ short f2bf(float f) {
    unsigned u = __builtin_bit_cast(unsigned, f);
    unsigned r = (u + 0x7fffu + ((u >> 16) & 1u)) >> 16;
    return (short)r;
}

__device__ __forceinline__ f32x4 mfma_bf16(bf16x8 a, bf16x8 b, f32x4 c) {
    return __builtin_amdgcn_mfma_f32_16x16x32_bf16(a, b, c, 0, 0, 0);
}

// ---- pack w_dcn (o,c,k) -> B-fragment order: [(ks*4+nf)*64+lane]*8+e
__global__ void pack_wdcn(const float* __restrict__ w_dcn, short* __restrict__ wtf) {
    int i = blockIdx.x * 256 + threadIdx.x;
    if (i >= 18 * 4 * 64 * 8) return;
    int e = i & 7, lane = (i >> 3) & 63, nf = (i >> 9) & 3, ks = i >> 11;
    int t = ks * 32 + ((lane >> 4) << 3) + e;
    int o = (nf << 4) + (lane & 15);
    int k = t >> 6, c = t & 63;
    wtf[i] = f2bf(w_dcn[(o * 64 + c) * 9 + k]);
}

// ---- pack w_off(18,c,k) + w_mask(9,c,k) -> [(ks*2+nf)*64+lane]*8+e, cols 27..31 zero
__global__ void pack_woff(const float* __restrict__ w_off, const float* __restrict__ w_mask,
                          short* __restrict__ wtf) {
    int i = blockIdx.x * 256 + threadIdx.x;
    if (i >= 18 * 2 * 64 * 8) return;
    int e = i & 7, lane = (i >> 3) & 63, nf = (i >> 9) & 1, ks = i >> 10;
    int t = ks * 32 + ((lane >> 4) << 3) + e;
    int oc = (nf << 4) + (lane & 15);
    int k = t >> 6, c = t & 63;
    float v = 0.f;
    if (oc < 18) v = w_off[(oc * 64 + c) * 9 + k];
    else if (oc < 27) v = w_mask[((oc - 18) * 64 + c) * 9 + k];
    wtf[i] = f2bf(v);
}

// ---------------- offset+mask conv: M=128 tile, B-frags from global per ks ----------------
__global__ __launch_bounds__(256) void off_mfma(
    const float* __restrict__ x, const short* __restrict__ wtf,
    const float* __restrict__ b_off, const float* __restrict__ b_mask,
    float* __restrict__ dyp, float* __restrict__ dxp, float* __restrict__ mkp)
{
    __shared__ __align__(16) short alds[2][4096];   // 128 px x 32 ch, double-buffered

    const int tid = threadIdx.x;
    const int bid = blockIdx.x;
    const int tile = (bid & 7) * 128 + (bid >> 3);   // 1024 blocks, XCD-bijective
    const int pbase = tile << 7;
    const int b = pbase / HW;
    const int rembase = pbase % HW;
    const float* xb = x + b * CIN * HW;

    // staging: this thread covers pixel px0 with channel-octets co0 and co0+2
    const int px0 = tid & 127, co0 = tid >> 7;
    const int rem = rembase + px0;
    const int hh = rem >> 7, wwp = rem & 127;
    const int slotA = ((px0 >> 4) * 64 + ((px0 & 15) | (co0 << 4))) * 8;
    const int slotB = slotA + 256;                   // (co0+2)<<4 lanes further

    auto stage = [&](int ks, int buf) {
        const int k = ks >> 1;
        const int cb = (ks & 1) << 5;
        int yy = hh + (k / 3) - 1;
        int xx = wwp + (k % 3) - 1;
        bool ok = (yy >= 0) && (yy < HH) && (xx >= 0) && (xx < WW);
        const float* xc0 = xb + (cb + co0 * 8) * HW + yy * WW + xx;
        bf16x8 v0, v1;
#pragma unroll
        for (int i = 0; i < 8; ++i) {
            v0[i] = f2bf(ok ? xc0[i * HW] : 0.f);
            v1[i] = f2bf(ok ? xc0[(i + 16) * HW] : 0.f);
        }
        *(bf16x8*)&alds[buf][slotA] = v0;
        *(bf16x8*)&alds[buf][slotB] = v1;
    };

    const int lane = tid & 63, wid = tid >> 6;
    const int nfw = wid & 1, mh = (wid >> 1) * 4;    // wave = (nf, m-half)

    f32x4 acc[4];
#pragma unroll
    for (int i = 0; i < 4; ++i) acc[i] = (f32x4){0.f, 0.f, 0.f, 0.f};

    stage(0, 0);
    int s = 0;
#pragma unroll 1
    for (int ks = 0; ks < 18; ++ks) {
        bf16x8 bc = *(const bf16x8*)&wtf[((((ks << 1) | nfw) * 64) + lane) * 8];
        __syncthreads();
        if (ks + 1 < 18) stage(ks + 1, s ^ 1);
#pragma unroll
        for (int i = 0; i < 4; ++i) {
            bf16x8 af = *(const bf16x8*)&alds[s][((mh + i) * 64 + lane) * 8];
            acc[i] = mfma_bf16(af, bc, acc[i]);
        }
        s ^= 1;
    }

    const int colb = lane & 15, rq = lane >> 4;
    const int oc = nfw * 16 + colb;
#pragma unroll
    for (int i = 0; i < 4; ++i) {
        int prow = (mh + i) * 16 + rq * 4;
        if (oc < 18) {
            int k = oc >> 1;
            float bo = b_off[oc];
            float* dst = ((oc & 1) ? dxp : dyp) + (b * 9 + k) * HW + rembase + prow;
#pragma unroll
            for (int j = 0; j < 4; ++j) dst[j] = acc[i][j] + bo;
        } else if (oc < 27) {
            int k = oc - 18;
            float bo = b_mask[k];
            float* dst = mkp + (b * 9 + k) * HW + rembase + prow;
#pragma unroll
            for (int j = 0; j < 4; ++j) dst[j] = 1.f / (1.f + expf(-(acc[i][j] + bo)));
        }
    }
}

// ---------------- deformable conv: M=64 tile, bilinear reused across k-halves ----------------
__global__ __launch_bounds__(256) void dcn_mfma(
    const float* __restrict__ x, const short* __restrict__ wtf,
    const float* __restrict__ dyp, const float* __restrict__ dxp,
    const float* __restrict__ mkp, const float* __restrict__ b_dcn,
    float* __restrict__ pre)
{
    __shared__ __align__(16) short alds[2][2048];   // buf0 = half0, buf1 = half1 (static roles)

    const int tid = threadIdx.x;
    const int bid = blockIdx.x;
    const int tile = (bid & 7) * 256 + (bid >> 3);   // 2048 blocks, XCD-bijective
    const int pbase = tile << 6;
    const int b = pbase / HW;
    const int rembase = pbase % HW;
    const int lanep = tid & 63;
    const int c_off = tid >> 6;
    const int rem = rembase + lanep;
    const int hh = rem >> 7, wwp = rem & 127;
    const float* xb = x + b * CIN * HW;
    const int slot = ((lanep >> 4) * 64 + ((lanep & 15) | (c_off << 4))) * 8;

    const int lane = tid & 63;
    const int nf = tid >> 6;                         // wave's 16-col N-fragment

    f32x4 acc[4];
#pragma unroll
    for (int i = 0; i < 4; ++i) acc[i] = (f32x4){0.f, 0.f, 0.f, 0.f};

    // bilinear state, computed once per k, reused for both channel-halves
    float w00, w01, w10, w11;
    int o00, o01, o10, o11;
    auto computeWO = [&](float dyv, float dxv, float mv, int k) {
        float py = (float)(hh + (k / 3) - 1) + dyv;
        float px = (float)(wwp + (k % 3) - 1) + dxv;
        float y0f = floorf(py), x0f = floorf(px);
        float ly = py - y0f, lx = px - x0f;
        int y0 = (int)y0f, x0 = (int)x0f;
        int y1 = y0 + 1, x1 = x0 + 1;
        float fy0 = (y0 >= 0 && y0 < HH) ? 1.f : 0.f;
        float fy1 = (y1 >= 0 && y1 < HH) ? 1.f : 0.f;
        float fx0 = (x0 >= 0 && x0 < WW) ? 1.f : 0.f;
        float fx1 = (x1 >= 0 && x1 < WW) ? 1.f : 0.f;
        int yc0 = min(max(y0, 0), HH - 1), yc1 = min(max(y1, 0), HH - 1);
        int xc0 = min(max(x0, 0), WW - 1), xc1 = min(max(x1, 0), WW - 1);
        o00 = yc0 * WW + xc0; o01 = yc0 * WW + xc1;
        o10 = yc1 * WW + xc0; o11 = yc1 * WW + xc1;
        w00 = (1.f - ly) * (1.f - lx) * mv * fy0 * fx0;
        w01 = (1.f - ly) * lx * mv * fy0 * fx1;
        w10 = ly * (1.f - lx) * mv * fy1 * fx0;
        w11 = ly * lx * mv * fy1 * fx1;
    };
    auto gstage = [&](int half, int buf) {
        const float* xc = xb + (half * 32 + c_off * 8) * HW;
        bf16x8 vals;
#pragma unroll
        for (int i = 0; i < 8; ++i) {
            float v = xc[o00] * w00 + xc[o01] * w01 + xc[o10] * w10 + xc[o11] * w11;
            vals[i] = f2bf(v);
            xc += HW;
        }
        *(bf16x8*)&alds[buf][slot] = vals;
    };

    // prologue: offsets + half0 of k=0 into buf0
    {
        int idx = b * 9 * HW + rem;
        computeWO(dyp[idx], dxp[idx], mkp[idx], 0);
    }
    gstage(0, 0);

#pragma unroll 1
    for (int k = 0; k < 9; ++k) {
        float dyn_ = 0.f, dxn_ = 0.f, mn_ = 0.f;
        if (k < 8) {                                  // prefetch next-k offsets
            int idx = (b * 9 + k + 1) * HW + rem;
            dyn_ = dyp[idx]; dxn_ = dxp[idx]; mn_ = mkp[idx];
        }
        bf16x8 b0 = *(const bf16x8*)&wtf[(((2 * k) * 4 + nf) * 64 + lane) * 8];
        bf16x8 b1 = *(const bf16x8*)&wtf[(((2 * k + 1) * 4 + nf) * 64 + lane) * 8];

        __syncthreads();                              // buf0(half0,k) ready; buf1 reads done
        gstage(1, 1);                                 // stage half1 of k
#pragma unroll
        for (int i = 0; i < 4; ++i) {
            bf16x8 af = *(const bf16x8*)&alds[0][(i * 64 + lane) * 8];
            acc[i] = mfma_bf16(af, b0, acc[i]);
        }
        __syncthreads();                              // buf1 ready; buf0 reads done
        if (k < 8) {
            computeWO(dyn_, dxn_, mn_, k + 1);
            gstage(0, 0);                             // stage half0 of k+1
        }
#pragma unroll
        for (int i = 0; i < 4; ++i) {
            bf16x8 af = *(const bf16x8*)&alds[1][(i * 64 + lane) * 8];
            acc[i] = mfma_bf16(af, b1, acc[i]);
        }
    }

    // epilogue: C/D map col=lane&15, row=(lane>>4)*4+j
    const int colb = lane & 15, rq = lane >> 4;
    const int o = nf * 16 + colb;
    const float bo = b_dcn[o];
    float* dst = pre + (b * COUT + o) * HW + rembase;
#pragma unroll
    for (int i = 0; i < 4; ++i) {
#pragma unroll
        for (int j = 0; j < 4; ++j) dst[i * 16 + rq * 4 + j] = acc[i][j] + bo;
    }
}

// ---------------- BN statistics ----------------
__global__ __launch_bounds__(256) void bn_stats(
    const float* __restrict__ pre, float* __restrict__ sums, float* __restrict__ sums2)
{
    int c = blockIdx.x & 63;
    int q = blockIdx.x >> 6;
    float s = 0.f, s2 = 0.f;
    for (int b = 0; b < BB; ++b) {
        const f32x4* p = (const f32x4*)(pre + (b * COUT + c) * HW + q * 4096);
        for (int i = threadIdx.x; i < 1024; i += 256) {
            f32x4 v = p[i];
            s += v.x + v.y + v.z + v.w;
            s2 += v.x * v.x + v.y * v.y + v.z * v.z + v.w * v.w;
        }
    }
#pragma unroll
    for (int off = 32; off > 0; off >>= 1) {
        s  += __shfl_down(s, off);
        s2 += __shfl_down(s2, off);
    }
    __shared__ float ls[8];
    int wid = threadIdx.x >> 6, lanei = threadIdx.x & 63;
    if (lanei == 0) { ls[wid] = s; ls[wid + 4] = s2; }
    __syncthreads();
    if (threadIdx.x == 0) {
        atomicAdd(&sums[c],  ls[0] + ls[1] + ls[2] + ls[3]);
        atomicAdd(&sums2[c], ls[4] + ls[5] + ls[6] + ls[7]);
    }
}

// ---------------- BN apply + Mish (float4) ----------------
__global__ __launch_bounds__(256) void bn_mish(
    const float* __restrict__ pre, const float* __restrict__ sums,
    const float* __restrict__ sums2, const float* __restrict__ gamma,
    const float* __restrict__ beta, float* __restrict__ out)
{
    int vid = blockIdx.x * 256 + threadIdx.x;
    int c = (vid >> 12) & 63;
    const float invN = 1.f / (float)(BB * HW);
    float mean = sums[c] * invN;
    float rstd = rsqrtf(sums2[c] * invN - mean * mean + EPSV);
    float g = gamma[c], be = beta[c];
    f32x4 v = ((const f32x4*)pre)[vid];
    f32x4 r;
#pragma unroll
    for (int j = 0; j < 4; ++j) {
        float t = (v[j] - mean) * rstd * g + be;
        float sp = fmaxf(t, 0.f) + log1pf(expf(-fabsf(t)));
        r[j] = t * tanhf(sp);
    }
    ((f32x4*)out)[vid] = r;
}

extern "C" void kernel_launch(void* const* d_in, const int* in_sizes, int n_in,
                              void* d_out, int out_size, void* d_ws, size_t ws_size,
                              hipStream_t stream) {
    const float* x      = (const float*)d_in[0];
    const float* w_off  = (const float*)d_in[1];
    const float* b_off  = (const float*)d_in[2];
    const float* w_mask = (const float*)d_in[3];
    const float* b_mask = (const float*)d_in[4];
    const float* w_dcn  = (const float*)d_in[5];
    const float* b_dcn  = (const float*)d_in[6];
    const float* gamma  = (const float*)d_in[7];
    const float* beta   = (const float*)d_in[8];
    float* out = (float*)d_out;

    short* wtf_off = (short*)d_ws;                    // 18432 shorts
    short* wtf_dcn = wtf_off + 18432;                 // 36864 shorts
    float* fws  = (float*)(wtf_dcn + 36864);          // 16B-aligned
    float* dyp  = fws;                                // 1179648
    float* dxp  = dyp + 1179648;
    float* mkp  = dxp + 1179648;
    float* prep = mkp + 1179648;                      // 8388608
    float* sums = prep + 8388608;
    float* sums2 = sums + 64;

    hipMemsetAsync(sums, 0, 2 * 64 * sizeof(float), stream);

    pack_woff<<<72, 256, 0, stream>>>(w_off, w_mask, wtf_off);
    pack_wdcn<<<144, 256, 0, stream>>>(w_dcn, wtf_dcn);
    off_mfma<<<1024, 256, 0, stream>>>(x, wtf_off, b_off, b_mask, dyp, dxp, mkp);
    dcn_mfma<<<2048, 256, 0, stream>>>(x, wtf_dcn, dyp, dxp, mkp, b_dcn, prep);
    bn_stats<<<256, 256, 0, stream>>>(prep, sums, sums2);
    bn_mish<<<8192, 256, 0, stream>>>(prep, sums, sums2, gamma, beta, out);
}

// Round 4
// 127.244 us; speedup vs baseline: 6.1198x; 2.0333x over previous
//
#include <hip/hip_runtime.h>
#include <math.h>

#define BB 8
#define CIN 64
#define COUT 64
#define HH 128
#define WW 128
#define HW (HH*WW)
#define EPSV 1e-5f

typedef __attribute__((ext_vector_type(8))) short bf16x8;
typedef __attribute__((ext_vector_type(4))) float f32x4;

__device__ __forceinline__ short f2bf(float f) {
    unsigned u = __builtin_bit_cast(unsigned, f);
    unsigned r = (u + 0x7fffu + ((u >> 16) & 1u)) >> 16;
    return (short)r;
}
__device__ __forceinline__ float b2f(short s) {
    return __builtin_bit_cast(float, ((unsigned)(unsigned short)s) << 16);
}
__device__ __forceinline__ f32x4 mfma_bf16(bf16x8 a, bf16x8 b, f32x4 c) {
    return __builtin_amdgcn_mfma_f32_16x16x32_bf16(a, b, c, 0, 0, 0);
}

// ---- pack w_dcn (o,c,k) -> B-fragment order: [(ks*4+nf)*64+lane]*8+e
__global__ void pack_wdcn(const float* __restrict__ w_dcn, short* __restrict__ wtf) {
    int i = blockIdx.x * 256 + threadIdx.x;
    if (i >= 18 * 4 * 64 * 8) return;
    int e = i & 7, lane = (i >> 3) & 63, nf = (i >> 9) & 3, ks = i >> 11;
    int t = ks * 32 + ((lane >> 4) << 3) + e;
    int o = (nf << 4) + (lane & 15);
    int k = t >> 6, c = t & 63;
    wtf[i] = f2bf(w_dcn[(o * 64 + c) * 9 + k]);
}

// ---- pack w_off(18,c,k) + w_mask(9,c,k) -> [(ks*2+nf)*64+lane]*8+e, cols 27..31 zero
__global__ void pack_woff(const float* __restrict__ w_off, const float* __restrict__ w_mask,
                          short* __restrict__ wtf) {
    int i = blockIdx.x * 256 + threadIdx.x;
    if (i >= 18 * 2 * 64 * 8) return;
    int e = i & 7, lane = (i >> 3) & 63, nf = (i >> 9) & 1, ks = i >> 10;
    int t = ks * 32 + ((lane >> 4) << 3) + e;
    int oc = (nf << 4) + (lane & 15);
    int k = t >> 6, c = t & 63;
    float v = 0.f;
    if (oc < 18) v = w_off[(oc * 64 + c) * 9 + k];
    else if (oc < 27) v = w_mask[((oc - 18) * 64 + c) * 9 + k];
    wtf[i] = f2bf(v);
}

// ---- transpose x NCHW f32 -> NHWC bf16 (xt[b][h][w][c]) ----
__global__ __launch_bounds__(256) void transpose_x(const float* __restrict__ x,
                                                   short* __restrict__ xt) {
    __shared__ short tl[4096];          // [w][c] with XOR swizzle
    const int t = threadIdx.x;
    const int blk = blockIdx.x;         // 2048 = 8b * 128h * 2wtiles
    const int b = blk >> 8, rem = blk & 255, h = rem >> 1, wb = (rem & 1) << 6;
    const int w4 = t & 15, ci = t >> 4; // 16 w-quads x 16 c-slots
#pragma unroll
    for (int i = 0; i < 4; ++i) {
        int c = i * 16 + ci;
        f32x4 v = *(const f32x4*)(x + (((b * 64 + c) * 128 + h) * 128) + wb + w4 * 4);
#pragma unroll
        for (int j = 0; j < 4; ++j) {
            int w = w4 * 4 + j;
            tl[w * 64 + (c ^ ((w & 7) << 3))] = f2bf(v[j]);
        }
    }
    __syncthreads();
    const int p = t >> 2, q = t & 3;
    bf16x8 a = *(const bf16x8*)&tl[p * 64 + ((q * 16) ^ ((p & 7) << 3))];
    bf16x8 bv = *(const bf16x8*)&tl[p * 64 + ((q * 16 + 8) ^ ((p & 7) << 3))];
    short* dst = xt + ((((b << 7) | h) << 7) | (wb + p)) * 64 + q * 16;
    *(bf16x8*)dst = a;
    *(bf16x8*)(dst + 8) = bv;
}

// ---------------- offset+mask conv on NHWC bf16 ----------------
__global__ __launch_bounds__(256) void off_mfma(
    const short* __restrict__ xt, const short* __restrict__ wtf,
    const float* __restrict__ b_off, const float* __restrict__ b_mask,
    float* __restrict__ dyp, float* __restrict__ dxp, float* __restrict__ mkp)
{
    __shared__ __align__(16) short alds[2][4096];
    const int tid = threadIdx.x;
    const int bid = blockIdx.x;
    const int tile = (bid & 7) * 256 + (bid >> 3);    // 2048 blocks, XCD-bijective
    const int pbase = tile << 6;
    const int b = pbase / HW;
    const int rembase = pbase % HW;
    const int hh0 = rembase >> 7;
    const int wb0 = rembase & 127;
    // staging role
    const int p = tid >> 2, q = tid & 3;
    const int wp0 = wb0 + p;
    // mfma role
    const int lane = tid & 63, wv = tid >> 6;
    const int nfw = wv & 1, mh = wv >> 1;

    f32x4 acc[2];
#pragma unroll
    for (int i = 0; i < 2; ++i) acc[i] = (f32x4){0.f, 0.f, 0.f, 0.f};

    bf16x8 z = {0, 0, 0, 0, 0, 0, 0, 0};
    bf16x8 s0v, s1v;
    auto issue = [&](int k) {
        int yy = hh0 + (k / 3) - 1;
        int xx = wp0 + (k % 3) - 1;
        bool ok = (yy >= 0) && (yy < HH) && (xx >= 0) && (xx < WW);
        const short* src = xt + ((((b << 7) | (yy & 127)) << 7) | (xx & 127)) * 64 + q * 16;
        s0v = ok ? *(const bf16x8*)src : z;
        s1v = ok ? *(const bf16x8*)(src + 8) : z;
    };
    const int ws0 = p * 64 + ((q * 16) ^ ((p & 7) << 3));
    const int ws1 = p * 64 + ((q * 16 + 8) ^ ((p & 7) << 3));
    auto writeStage = [&](int buf) {
        *(bf16x8*)&alds[buf][ws0] = s0v;
        *(bf16x8*)&alds[buf][ws1] = s1v;
    };

    issue(0);
    writeStage(0);
    __syncthreads();
    int s = 0;
#pragma unroll 1
    for (int k = 0; k < 9; ++k) {
        if (k < 8) issue(k + 1);
        bf16x8 b0 = *(const bf16x8*)&wtf[(((2 * k) * 2 + nfw) * 64 + lane) * 8];
        bf16x8 b1 = *(const bf16x8*)&wtf[(((2 * k + 1) * 2 + nfw) * 64 + lane) * 8];
#pragma unroll
        for (int kh = 0; kh < 2; ++kh) {
            bf16x8 bb = kh ? b1 : b0;
#pragma unroll
            for (int i = 0; i < 2; ++i) {
                int px = (mh * 2 + i) * 16 + (lane & 15);
                int sidx = px * 64 + ((kh * 32 + ((lane >> 4) << 3)) ^ ((px & 7) << 3));
                bf16x8 af = *(const bf16x8*)&alds[s][sidx];
                acc[i] = mfma_bf16(af, bb, acc[i]);
            }
        }
        if (k < 8) {
            __syncthreads();
            writeStage(s ^ 1);
            __syncthreads();
            s ^= 1;
        }
    }

    const int colb = lane & 15, rq = lane >> 4;
    const int oc = nfw * 16 + colb;
#pragma unroll
    for (int i = 0; i < 2; ++i) {
        int prow = (mh * 2 + i) * 16 + rq * 4;
        if (oc < 18) {
            int k = oc >> 1;
            float bo = b_off[oc];
            float* dst = ((oc & 1) ? dxp : dyp) + (b * 9 + k) * HW + rembase + prow;
#pragma unroll
            for (int j = 0; j < 4; ++j) dst[j] = acc[i][j] + bo;
        } else if (oc < 27) {
            int k = oc - 18;
            float bo = b_mask[k];
            float* dst = mkp + (b * 9 + k) * HW + rembase + prow;
#pragma unroll
            for (int j = 0; j < 4; ++j) dst[j] = 1.f / (1.f + expf(-(acc[i][j] + bo)));
        }
    }
}

// ---------------- deformable conv on NHWC bf16 ----------------
struct Stage {
    float w00, w01, w10, w11;
    bf16x8 c00a, c00b, c01a, c01b, c10a, c10b, c11a, c11b;
};

__global__ __launch_bounds__(256) void dcn_mfma(
    const short* __restrict__ xt, const short* __restrict__ wtf,
    const float* __restrict__ dyp, const float* __restrict__ dxp,
    const float* __restrict__ mkp, const float* __restrict__ b_dcn,
    float* __restrict__ pre)
{
    __shared__ __align__(16) short alds[2][4096];
    const int tid = threadIdx.x;
    const int bid = blockIdx.x;
    const int tile = (bid & 7) * 256 + (bid >> 3);    // 2048 blocks
    const int pbase = tile << 6;
    const int b = pbase / HW;
    const int rembase = pbase % HW;
    // staging role
    const int p = tid >> 2, q = tid & 3;
    const int remp = rembase + p;
    const int hh = remp >> 7, wp = remp & 127;
    const int offbase = b * 9 * HW + remp;
    // mfma role
    const int lane = tid & 63, nf = tid >> 6;

    f32x4 acc[4];
#pragma unroll
    for (int i = 0; i < 4; ++i) acc[i] = (f32x4){0.f, 0.f, 0.f, 0.f};

    float dyn, dxn, mn;
    auto loadoffs = [&](int k) {
        dyn = dyp[offbase + k * HW];
        dxn = dxp[offbase + k * HW];
        mn  = mkp[offbase + k * HW];
    };
    auto issue = [&](int k) -> Stage {
        Stage st;
        float py = (float)(hh + (k / 3) - 1) + dyn;
        float px = (float)(wp + (k % 3) - 1) + dxn;
        float y0f = floorf(py), x0f = floorf(px);
        float ly = py - y0f, lx = px - x0f;
        int y0 = (int)y0f, x0 = (int)x0f;
        int y1 = y0 + 1, x1 = x0 + 1;
        float fy0 = (y0 >= 0 && y0 < HH) ? 1.f : 0.f;
        float fy1 = (y1 >= 0 && y1 < HH) ? 1.f : 0.f;
        float fx0 = (x0 >= 0 && x0 < WW) ? 1.f : 0.f;
        float fx1 = (x1 >= 0 && x1 < WW) ? 1.f : 0.f;
        int yc0 = min(max(y0, 0), HH - 1), yc1 = min(max(y1, 0), HH - 1);
        int xc0 = min(max(x0, 0), WW - 1), xc1 = min(max(x1, 0), WW - 1);
        st.w00 = (1.f - ly) * (1.f - lx) * mn * fy0 * fx0;
        st.w01 = (1.f - ly) * lx * mn * fy0 * fx1;
        st.w10 = ly * (1.f - lx) * mn * fy1 * fx0;
        st.w11 = ly * lx * mn * fy1 * fx1;
        const short* s00 = xt + (((b << 7) | yc0) << 7 | xc0) * 64 + q * 16;
        const short* s01 = xt + (((b << 7) | yc0) << 7 | xc1) * 64 + q * 16;
        const short* s10 = xt + (((b << 7) | yc1) << 7 | xc0) * 64 + q * 16;
        const short* s11 = xt + (((b << 7) | yc1) << 7 | xc1) * 64 + q * 16;
        st.c00a = *(const bf16x8*)s00; st.c00b = *(const bf16x8*)(s00 + 8);
        st.c01a = *(const bf16x8*)s01; st.c01b = *(const bf16x8*)(s01 + 8);
        st.c10a = *(const bf16x8*)s10; st.c10b = *(const bf16x8*)(s10 + 8);
        st.c11a = *(const bf16x8*)s11; st.c11b = *(const bf16x8*)(s11 + 8);
        return st;
    };
    const int ws0 = p * 64 + ((q * 16) ^ ((p & 7) << 3));
    const int ws1 = p * 64 + ((q * 16 + 8) ^ ((p & 7) << 3));
    auto writeStage = [&](const Stage& st, int buf) {
        bf16x8 oa, ob;
#pragma unroll
        for (int j = 0; j < 8; ++j) {
            float va = b2f(st.c00a[j]) * st.w00 + b2f(st.c01a[j]) * st.w01
                     + b2f(st.c10a[j]) * st.w10 + b2f(st.c11a[j]) * st.w11;
            float vb = b2f(st.c00b[j]) * st.w00 + b2f(st.c01b[j]) * st.w01
                     + b2f(st.c10b[j]) * st.w10 + b2f(st.c11b[j]) * st.w11;
            oa[j] = f2bf(va);
            ob[j] = f2bf(vb);
        }
        *(bf16x8*)&alds[buf][ws0] = oa;
        *(bf16x8*)&alds[buf][ws1] = ob;
    };

    // prologue
    loadoffs(0);
    Stage st0 = issue(0);
    writeStage(st0, 0);
    loadoffs(1);
    __syncthreads();
    int s = 0;
#pragma unroll 1
    for (int k = 0; k < 9; ++k) {
        Stage nst;
        if (k < 8) {
            nst = issue(k + 1);               // corner loads in flight under MFMA
            if (k < 7) loadoffs(k + 2);
        }
        bf16x8 b0 = *(const bf16x8*)&wtf[(((2 * k) * 4 + nf) * 64 + lane) * 8];
        bf16x8 b1 = *(const bf16x8*)&wtf[(((2 * k + 1) * 4 + nf) * 64 + lane) * 8];
#pragma unroll
        for (int kh = 0; kh < 2; ++kh) {
            bf16x8 bb = kh ? b1 : b0;
#pragma unroll
            for (int mb = 0; mb < 4; ++mb) {
                int px = mb * 16 + (lane & 15);
                int sidx = px * 64 + ((kh * 32 + ((lane >> 4) << 3)) ^ ((px & 7) << 3));
                bf16x8 af = *(const bf16x8*)&alds[s][sidx];
                acc[mb] = mfma_bf16(af, bb, acc[mb]);
            }
        }
        if (k < 8) {
            __syncthreads();
            writeStage(nst, s ^ 1);
            __syncthreads();
            s ^= 1;
        }
    }

    const int colb = lane & 15, rq = lane >> 4;
    const int o = nf * 16 + colb;
    const float bo = b_dcn[o];
    float* dst = pre + (b * COUT + o) * HW + rembase;
#pragma unroll
    for (int mb = 0; mb < 4; ++mb) {
#pragma unroll
        for (int j = 0; j < 4; ++j) dst[mb * 16 + rq * 4 + j] = acc[mb][j] + bo;
    }
}

// ---------------- BN statistics ----------------
__global__ __launch_bounds__(256) void bn_stats(
    const float* __restrict__ pre, float* __restrict__ sums, float* __restrict__ sums2)
{
    int c = blockIdx.x & 63;
    int qq = blockIdx.x >> 6;
    float s = 0.f, s2 = 0.f;
    for (int b = 0; b < BB; ++b) {
        const f32x4* p = (const f32x4*)(pre + (b * COUT + c) * HW + qq * 4096);
        for (int i = threadIdx.x; i < 1024; i += 256) {
            f32x4 v = p[i];
            s += v.x + v.y + v.z + v.w;
            s2 += v.x * v.x + v.y * v.y + v.z * v.z + v.w * v.w;
        }
    }
#pragma unroll
    for (int off = 32; off > 0; off >>= 1) {
        s  += __shfl_down(s, off);
        s2 += __shfl_down(s2, off);
    }
    __shared__ float ls[8];
    int wid = threadIdx.x >> 6, lanei = threadIdx.x & 63;
    if (lanei == 0) { ls[wid] = s; ls[wid + 4] = s2; }
    __syncthreads();
    if (threadIdx.x == 0) {
        atomicAdd(&sums[c],  ls[0] + ls[1] + ls[2] + ls[3]);
        atomicAdd(&sums2[c], ls[4] + ls[5] + ls[6] + ls[7]);
    }
}

// ---------------- BN apply + Mish (float4) ----------------
__global__ __launch_bounds__(256) void bn_mish(
    const float* __restrict__ pre, const float* __restrict__ sums,
    const float* __restrict__ sums2, const float* __restrict__ gamma,
    const float* __restrict__ beta, float* __restrict__ out)
{
    int vid = blockIdx.x * 256 + threadIdx.x;
    int c = (vid >> 12) & 63;
    const float invN = 1.f / (float)(BB * HW);
    float mean = sums[c] * invN;
    float rstd = rsqrtf(sums2[c] * invN - mean * mean + EPSV);
    float g = gamma[c], be = beta[c];
    f32x4 v = ((const f32x4*)pre)[vid];
    f32x4 r;
#pragma unroll
    for (int j = 0; j < 4; ++j) {
        float t = (v[j] - mean) * rstd * g + be;
        float sp = fmaxf(t, 0.f) + log1pf(expf(-fabsf(t)));
        r[j] = t * tanhf(sp);
    }
    ((f32x4*)out)[vid] = r;
}

extern "C" void kernel_launch(void* const* d_in, const int* in_sizes, int n_in,
                              void* d_out, int out_size, void* d_ws, size_t ws_size,
                              hipStream_t stream) {
    const float* x      = (const float*)d_in[0];
    const float* w_off  = (const float*)d_in[1];
    const float* b_off  = (const float*)d_in[2];
    const float* w_mask = (const float*)d_in[3];
    const float* b_mask = (const float*)d_in[4];
    const float* w_dcn  = (const float*)d_in[5];
    const float* b_dcn  = (const float*)d_in[6];
    const float* gamma  = (const float*)d_in[7];
    const float* beta   = (const float*)d_in[8];
    float* out = (float*)d_out;

    short* wtf_off = (short*)d_ws;                    // 18432 shorts
    short* wtf_dcn = wtf_off + 18432;                 // 36864 shorts
    short* xt      = wtf_dcn + 36864;                 // 8388608 shorts (NHWC bf16)
    float* fws  = (float*)(xt + 8388608);             // 16B-aligned
    float* dyp  = fws;                                // 1179648
    float* dxp  = dyp + 1179648;
    float* mkp  = dxp + 1179648;
    float* prep = mkp + 1179648;                      // 8388608
    float* sums = prep + 8388608;
    float* sums2 = sums + 64;

    hipMemsetAsync(sums, 0, 2 * 64 * sizeof(float), stream);

    pack_woff<<<72, 256, 0, stream>>>(w_off, w_mask, wtf_off);
    pack_wdcn<<<144, 256, 0, stream>>>(w_dcn, wtf_dcn);
    transpose_x<<<2048, 256, 0, stream>>>(x, xt);
    off_mfma<<<2048, 256, 0, stream>>>(xt, wtf_off, b_off, b_mask, dyp, dxp, mkp);
    dcn_mfma<<<2048, 256, 0, stream>>>(xt, wtf_dcn, dyp, dxp, mkp, b_dcn, prep);
    bn_stats<<<256, 256, 0, stream>>>(prep, sums, sums2);
    bn_mish<<<8192, 256, 0, stream>>>(prep, sums, sums2, gamma, beta, out);
}

// Round 5
// 109.521 us; speedup vs baseline: 7.1101x; 1.1618x over previous
//
#include <hip/hip_runtime.h>
#include <math.h>

#define BB 8
#define HH 128
#define WW 128
#define HW (HH*WW)
#define EPSV 1e-5f

typedef __attribute__((ext_vector_type(8))) _Float16 f16x8;
typedef __attribute__((ext_vector_type(4))) float f32x4;

__device__ __forceinline__ short f2h(float f) {
    _Float16 h = (_Float16)f;
    return __builtin_bit_cast(short, h);
}
__device__ __forceinline__ f32x4 mfma_f16(f16x8 a, f16x8 b, f32x4 c) {
    return __builtin_amdgcn_mfma_f32_16x16x32_f16(a, b, c, 0, 0, 0);
}

// ---- pack both weight tensors to fp16 B-fragment order ----
__global__ void pack_all(const float* __restrict__ w_dcn, const float* __restrict__ w_off,
                         const float* __restrict__ w_mask,
                         short* __restrict__ wtf_dcn, short* __restrict__ wtf_off) {
    int i = blockIdx.x * 256 + threadIdx.x;
    if (i < 36864) {                       // w_dcn: [(ks*4+nf)*64+lane]*8+e
        int e = i & 7, lane = (i >> 3) & 63, nf = (i >> 9) & 3, ks = i >> 11;
        int t = ks * 32 + ((lane >> 4) << 3) + e;
        int o = (nf << 4) + (lane & 15);
        int k = t >> 6, c = t & 63;
        wtf_dcn[i] = f2h(w_dcn[(o * 64 + c) * 9 + k]);
    } else if (i < 36864 + 18432) {        // w_off/w_mask: [(ks*2+nf)*64+lane]*8+e
        int j = i - 36864;
        int e = j & 7, lane = (j >> 3) & 63, nf = (j >> 9) & 1, ks = j >> 10;
        int t = ks * 32 + ((lane >> 4) << 3) + e;
        int oc = (nf << 4) + (lane & 15);
        int k = t >> 6, c = t & 63;
        float v = 0.f;
        if (oc < 18) v = w_off[(oc * 64 + c) * 9 + k];
        else if (oc < 27) v = w_mask[((oc - 18) * 64 + c) * 9 + k];
        wtf_off[j] = f2h(v);
    }
}

// ---- transpose x NCHW f32 -> NHWC fp16 (xt[b][h][w][c]) ----
__global__ __launch_bounds__(256) void transpose_x(const float* __restrict__ x,
                                                   short* __restrict__ xt) {
    __shared__ short tl[4096];
    const int t = threadIdx.x;
    const int blk = blockIdx.x;         // 2048 = 8b * 128h * 2wtiles
    const int b = blk >> 8, rem = blk & 255, h = rem >> 1, wb = (rem & 1) << 6;
    const int w4 = t & 15, ci = t >> 4;
#pragma unroll
    for (int i = 0; i < 4; ++i) {
        int c = i * 16 + ci;
        f32x4 v = *(const f32x4*)(x + (((b * 64 + c) * 128 + h) * 128) + wb + w4 * 4);
#pragma unroll
        for (int j = 0; j < 4; ++j) {
            int w = w4 * 4 + j;
            tl[w * 64 + (c ^ ((w & 7) << 3))] = f2h(v[j]);
        }
    }
    __syncthreads();
    const int p = t >> 2, q = t & 3;
    f16x8 a = *(const f16x8*)&tl[p * 64 + ((q * 16) ^ ((p & 7) << 3))];
    f16x8 bv = *(const f16x8*)&tl[p * 64 + ((q * 16 + 8) ^ ((p & 7) << 3))];
    short* dst = xt + ((((b << 7) | h) << 7) | (wb + p)) * 64 + q * 16;
    *(f16x8*)dst = a;
    *(f16x8*)(dst + 8) = bv;
}

// ---------------- fused: off/mask conv -> LDS offsets -> deformable conv + BN partials ----------------
__global__ __launch_bounds__(256) void fused_conv(
    const short* __restrict__ xt,
    const short* __restrict__ wtf_off, const short* __restrict__ wtf_dcn,
    const float* __restrict__ b_off, const float* __restrict__ b_mask,
    const float* __restrict__ b_dcn,
    float* __restrict__ pre, float* __restrict__ sums_p)
{
    __shared__ __align__(16) short alds[4096];     // [64px][64ch] fp16 A-tile (single buffer)
    __shared__ float offy[9][64], offxl[9][64], offmm[9][64];

    const int tid = threadIdx.x;
    const int bid = blockIdx.x;
    const int tile = (bid & 7) * 256 + (bid >> 3);  // XCD-bijective, 2048 % 8 == 0
    const int pbase = tile << 6;
    const int b = pbase / HW;
    const int rembase = pbase % HW;
    const int hh0 = rembase >> 7;
    const int wb0 = rembase & 127;
    const int p = tid >> 2, q = tid & 3;            // staging role: pixel p, 16-ch group q
    const int wp0 = wb0 + p;
    const int lane = tid & 63, wv = tid >> 6;

    const int ws0 = p * 64 + ((q * 16) ^ ((p & 7) << 3));
    const int ws1 = p * 64 + ((q * 16 + 8) ^ ((p & 7) << 3));

    // ================= Phase A: offset/mask conv (N=32) =================
    const int nfw = wv & 1, mh = wv >> 1;
    f16x8 s0v, s1v;
    auto issueND = [&](int k) {
        int yy = hh0 + (k / 3) - 1;
        int xx = wp0 + (k % 3) - 1;
        bool ok = (yy >= 0) && (yy < HH) && (xx >= 0) && (xx < WW);
        const short* src = xt + ((((b << 7) | (yy & 127)) << 7) | (xx & 127)) * 64 + q * 16;
        f16x8 z = {};
        s0v = ok ? *(const f16x8*)src : z;
        s1v = ok ? *(const f16x8*)(src + 8) : z;
    };
    auto writeND = [&]() {
        *(f16x8*)&alds[ws0] = s0v;
        *(f16x8*)&alds[ws1] = s1v;
    };

    f32x4 acc2[2];
    acc2[0] = (f32x4){0.f, 0.f, 0.f, 0.f};
    acc2[1] = acc2[0];

    issueND(0);
    writeND();
    __syncthreads();
#pragma unroll 1
    for (int k = 0; k < 9; ++k) {
        if (k < 8) issueND(k + 1);
        f16x8 b0 = *(const f16x8*)&wtf_off[(((2 * k) * 2 + nfw) * 64 + lane) * 8];
        f16x8 b1 = *(const f16x8*)&wtf_off[(((2 * k + 1) * 2 + nfw) * 64 + lane) * 8];
#pragma unroll
        for (int kh = 0; kh < 2; ++kh) {
            f16x8 bb = kh ? b1 : b0;
#pragma unroll
            for (int i = 0; i < 2; ++i) {
                int px = (mh * 2 + i) * 16 + (lane & 15);
                int sidx = px * 64 + ((kh * 32 + ((lane >> 4) << 3)) ^ ((px & 7) << 3));
                f16x8 af = *(const f16x8*)&alds[sidx];
                acc2[i] = mfma_f16(af, bb, acc2[i]);
            }
        }
        __syncthreads();
        if (k < 8) { writeND(); __syncthreads(); }
    }
    {   // epilogue A: offsets + sigmoid(mask) -> LDS
        const int colb = lane & 15, rq = lane >> 4;
        const int oc = nfw * 16 + colb;
#pragma unroll
        for (int i = 0; i < 2; ++i) {
#pragma unroll
            for (int j = 0; j < 4; ++j) {
                int px = (mh * 2 + i) * 16 + rq * 4 + j;
                float v = acc2[i][j];
                if (oc < 18) {
                    v += b_off[oc];
                    if (oc & 1) offxl[oc >> 1][px] = v; else offy[oc >> 1][px] = v;
                } else if (oc < 27) {
                    v += b_mask[oc - 18];
                    offmm[oc - 18][px] = 1.f / (1.f + expf(-v));
                }
            }
        }
    }
    __syncthreads();

    // ================= Phase B: deformable conv (N=64) =================
    const int nf = wv;
    f32x4 acc[4];
#pragma unroll
    for (int i = 0; i < 4; ++i) acc[i] = (f32x4){0.f, 0.f, 0.f, 0.f};

    f16x8 c00a, c00b, c01a, c01b, c10a, c10b, c11a, c11b;
    _Float16 h00, h01, h10, h11;
    auto issueB = [&](int k) {
        float dyv = offy[k][p], dxv = offxl[k][p], mv = offmm[k][p];
        float py = (float)(hh0 + (k / 3) - 1) + dyv;
        float pxf = (float)(wp0 + (k % 3) - 1) + dxv;
        float y0f = floorf(py), x0f = floorf(pxf);
        float ly = py - y0f, lx = pxf - x0f;
        int y0 = (int)y0f, x0 = (int)x0f;
        int y1 = y0 + 1, x1 = x0 + 1;
        float fy0 = (y0 >= 0 && y0 < HH) ? 1.f : 0.f;
        float fy1 = (y1 >= 0 && y1 < HH) ? 1.f : 0.f;
        float fx0 = (x0 >= 0 && x0 < WW) ? 1.f : 0.f;
        float fx1 = (x1 >= 0 && x1 < WW) ? 1.f : 0.f;
        int yc0 = min(max(y0, 0), HH - 1), yc1 = min(max(y1, 0), HH - 1);
        int xc0 = min(max(x0, 0), WW - 1), xc1 = min(max(x1, 0), WW - 1);
        h00 = (_Float16)((1.f - ly) * (1.f - lx) * mv * fy0 * fx0);
        h01 = (_Float16)((1.f - ly) * lx * mv * fy0 * fx1);
        h10 = (_Float16)(ly * (1.f - lx) * mv * fy1 * fx0);
        h11 = (_Float16)(ly * lx * mv * fy1 * fx1);
        const short* s00 = xt + ((((b << 7) | yc0) << 7) | xc0) * 64 + q * 16;
        const short* s01 = xt + ((((b << 7) | yc0) << 7) | xc1) * 64 + q * 16;
        const short* s10 = xt + ((((b << 7) | yc1) << 7) | xc0) * 64 + q * 16;
        const short* s11 = xt + ((((b << 7) | yc1) << 7) | xc1) * 64 + q * 16;
        c00a = *(const f16x8*)s00; c00b = *(const f16x8*)(s00 + 8);
        c01a = *(const f16x8*)s01; c01b = *(const f16x8*)(s01 + 8);
        c10a = *(const f16x8*)s10; c10b = *(const f16x8*)(s10 + 8);
        c11a = *(const f16x8*)s11; c11b = *(const f16x8*)(s11 + 8);
    };
    auto writeB = [&]() {        // packed-fp16 bilinear interp, no output cvt
        f16x8 va = c00a * h00 + c01a * h01 + c10a * h10 + c11a * h11;
        f16x8 vb = c00b * h00 + c01b * h01 + c10b * h10 + c11b * h11;
        *(f16x8*)&alds[ws0] = va;
        *(f16x8*)&alds[ws1] = vb;
    };

    issueB(0);
    writeB();
    __syncthreads();
#pragma unroll 1
    for (int k = 0; k < 9; ++k) {
        if (k < 8) issueB(k + 1);            // corner loads fly under MFMA
        f16x8 b0 = *(const f16x8*)&wtf_dcn[(((2 * k) * 4 + nf) * 64 + lane) * 8];
        f16x8 b1 = *(const f16x8*)&wtf_dcn[(((2 * k + 1) * 4 + nf) * 64 + lane) * 8];
#pragma unroll
        for (int kh = 0; kh < 2; ++kh) {
            f16x8 bb = kh ? b1 : b0;
#pragma unroll
            for (int mb = 0; mb < 4; ++mb) {
                int px = mb * 16 + (lane & 15);
                int sidx = px * 64 + ((kh * 32 + ((lane >> 4) << 3)) ^ ((px & 7) << 3));
                f16x8 af = *(const f16x8*)&alds[sidx];
                acc[mb] = mfma_f16(af, bb, acc[mb]);
            }
        }
        __syncthreads();
        if (k < 8) { writeB(); __syncthreads(); }
    }

    // epilogue B: bias + store pre + BN partial sums
    {
        const int colb = lane & 15, rq = lane >> 4;
        const int o = nf * 16 + colb;
        const float bo = b_dcn[o];
        float* dst = pre + (b * 64 + o) * HW + rembase;
        float s = 0.f, s2 = 0.f;
#pragma unroll
        for (int mb = 0; mb < 4; ++mb) {
#pragma unroll
            for (int j = 0; j < 4; ++j) {
                float v = acc[mb][j] + bo;
                dst[mb * 16 + rq * 4 + j] = v;
                s += v; s2 += v * v;
            }
        }
        s  += __shfl_xor(s, 16);  s  += __shfl_xor(s, 32);
        s2 += __shfl_xor(s2, 16); s2 += __shfl_xor(s2, 32);
        if (lane < 16) {
            int slot = bid & 31;
            atomicAdd(&sums_p[slot * 64 + o], s);
            atomicAdd(&sums_p[2048 + slot * 64 + o], s2);
        }
    }
}

// ---------------- BN apply + Mish (reduces 32 partial slots) ----------------
__global__ __launch_bounds__(256) void bn_mish(
    const float* __restrict__ pre, const float* __restrict__ sums_p,
    const float* __restrict__ gamma, const float* __restrict__ beta,
    float* __restrict__ out)
{
    const int c = (blockIdx.x >> 4) & 63;           // uniform per block
    float sm = 0.f, sq = 0.f;
#pragma unroll
    for (int s = 0; s < 32; ++s) {
        sm += sums_p[s * 64 + c];
        sq += sums_p[2048 + s * 64 + c];
    }
    const float invN = 1.f / (float)(BB * HW);
    float mean = sm * invN;
    float rstd = rsqrtf(sq * invN - mean * mean + EPSV);
    float g = gamma[c], be = beta[c];
    int vid = blockIdx.x * 256 + threadIdx.x;
    f32x4 v = ((const f32x4*)pre)[vid];
    f32x4 r;
#pragma unroll
    for (int j = 0; j < 4; ++j) {
        float t = (v[j] - mean) * rstd * g + be;
        float sp = fmaxf(t, 0.f) + log1pf(expf(-fabsf(t)));
        r[j] = t * tanhf(sp);
    }
    ((f32x4*)out)[vid] = r;
}

extern "C" void kernel_launch(void* const* d_in, const int* in_sizes, int n_in,
                              void* d_out, int out_size, void* d_ws, size_t ws_size,
                              hipStream_t stream) {
    const float* x      = (const float*)d_in[0];
    const float* w_off  = (const float*)d_in[1];
    const float* b_off  = (const float*)d_in[2];
    const float* w_mask = (const float*)d_in[3];
    const float* b_mask = (const float*)d_in[4];
    const float* w_dcn  = (const float*)d_in[5];
    const float* b_dcn  = (const float*)d_in[6];
    const float* gamma  = (const float*)d_in[7];
    const float* beta   = (const float*)d_in[8];
    float* out = (float*)d_out;

    float* sums_p  = (float*)d_ws;                  // 4096 floats (2 x 32 x 64)
    short* wtf_dcn = (short*)(sums_p + 4096);       // 36864 shorts
    short* wtf_off = wtf_dcn + 36864;               // 18432 shorts
    short* xt      = wtf_off + 18432;               // 8388608 shorts, offset 126976 B (16-aligned)
    float* prep    = (float*)(xt + 8388608);        // 8388608 floats

    hipMemsetAsync(sums_p, 0, 4096 * sizeof(float), stream);

    pack_all<<<216, 256, 0, stream>>>(w_dcn, w_off, w_mask, wtf_dcn, wtf_off);
    transpose_x<<<2048, 256, 0, stream>>>(x, xt);
    fused_conv<<<2048, 256, 0, stream>>>(xt, wtf_off, wtf_dcn, b_off, b_mask, b_dcn, prep, sums_p);
    bn_mish<<<8192, 256, 0, stream>>>(prep, sums_p, gamma, beta, out);
}